// Round 6
// baseline (629.840 us; speedup 1.0000x reference)
//
#include <hip/hip_runtime.h>
#include <hip/hip_bf16.h>

#define N_NODES 8192
#define NF      256
#define L2E     1.44269504088896341f

typedef __attribute__((ext_vector_type(8))) short short8;
typedef __attribute__((ext_vector_type(4))) short short4v;
typedef __attribute__((ext_vector_type(4))) float floatx4;

static __device__ __forceinline__ float bf2f(short s) {
    return __uint_as_float(((unsigned)(unsigned short)s) << 16);
}
static __device__ __forceinline__ short f2bf_rn(float f) {
    unsigned u = __float_as_uint(f) + 0x8000u;
    return (short)(u >> 16);
}
struct bfpair { short hi, lo; };
static __device__ __forceinline__ bfpair split_bf(float x) {
    bfpair p;
    p.hi = f2bf_rn(x);
    p.lo = f2bf_rn(x - bf2f(p.hi));
    return p;
}
// async global->LDS, 16B/lane, LDS dest = uniform base + lane*16
static __device__ __forceinline__ void async16(const void* g, void* l) {
    __builtin_amdgcn_global_load_lds(
        (const __attribute__((address_space(1))) unsigned*)g,
        (__attribute__((address_space(3))) unsigned*)l, 16, 0, 0);
}

// ---------------------------------------------------------------------------
// KX: split W (256x256 fp32) into bf16 hi/lo arrays, once.
// ---------------------------------------------------------------------------
__global__ __launch_bounds__(256) void kx_split(const float* __restrict__ W,
                                                short* __restrict__ Whi,
                                                short* __restrict__ Wlo) {
    #pragma unroll
    for (int e = 0; e < 4; ++e) {
        const int i = blockIdx.x * 1024 + e * 256 + threadIdx.x;
        bfpair p = split_bf(W[i]);
        Whi[i] = p.hi;
        Wlo[i] = p.lo;
    }
}

// ---------------------------------------------------------------------------
// K1: WhT[n][i] = sum_k X[i][k]*W[n][k] via hi/lo bf16 MFMA (fp32-accurate).
// Also emits per-cq partials of s_src/s_dst from fp32 accumulators.
// grid 256 (32 i-rows each) x 512 thr (8 waves = 2 rowhalf x 4 colquarter).
// X staged fp32 -> LDS (async16, 16B-chunk XOR swizzle), split in-register.
// ---------------------------------------------------------------------------
__global__ __launch_bounds__(512) void k1_gemm(const float* __restrict__ X,
                                               const short* __restrict__ Whi,
                                               const short* __restrict__ Wlo,
                                               const float* __restrict__ r,
                                               short* __restrict__ WhT,
                                               float* __restrict__ sp_src,
                                               float* __restrict__ sp_dst) {
    __shared__ float Xs[32 * 256];   // 32 KB; chunk slot = c ^ (row&7)

    const int tid = threadIdx.x;
    const int w = tid >> 6, lane = tid & 63;
    const int q = lane >> 4, m = lane & 15;
    const int rh = w >> 2, cq = w & 3;
    const int i_base = blockIdx.x * 32;

    // stage 32 rows of X (1 KB each); 4 instrs/wave
    #pragma unroll
    for (int v = 0; v < 4; ++v) {
        const int rowv = w * 4 + v;
        const int c = lane ^ (rowv & 7);
        async16(X + (size_t)(i_base + rowv) * NF + c * 4, &Xs[rowv * 256]);
    }
    __syncthreads();

    floatx4 acc[4] = {};
    const int xrow = rh * 16 + m;
    const int r7 = xrow & 7;
    #pragma unroll
    for (int ks = 0; ks < 8; ++ks) {
        const int c0 = ks * 8 + q * 2;
        float4 f0 = *(const float4*)(&Xs[xrow * 256 + ((c0 ^ r7) * 4)]);
        float4 f1 = *(const float4*)(&Xs[xrow * 256 + (((c0 + 1) ^ r7) * 4)]);
        const float xsv[8] = {f0.x, f0.y, f0.z, f0.w, f1.x, f1.y, f1.z, f1.w};
        short8 xh, xl;
        #pragma unroll
        for (int c = 0; c < 8; ++c) {
            bfpair p = split_bf(xsv[c]);
            xh[c] = p.hi; xl[c] = p.lo;
        }
        #pragma unroll
        for (int nt = 0; nt < 4; ++nt) {
            const int n = cq * 64 + nt * 16 + m;
            short8 wh = *(const short8*)(Whi + n * NF + ks * 32 + q * 8);
            short8 wl = *(const short8*)(Wlo + n * NF + ks * 32 + q * 8);
            acc[nt] = __builtin_amdgcn_mfma_f32_16x16x32_bf16(xh, wh, acc[nt], 0, 0, 0);
            acc[nt] = __builtin_amdgcn_mfma_f32_16x16x32_bf16(xl, wh, acc[nt], 0, 0, 0);
            acc[nt] = __builtin_amdgcn_mfma_f32_16x16x32_bf16(xh, wl, acc[nt], 0, 0, 0);
        }
    }

    // C/D layout: col = lane&15 (n), row = q*4 + reg (i)
    const int i0 = i_base + rh * 16 + q * 4;
    float vs[4] = {0.f, 0.f, 0.f, 0.f}, vd[4] = {0.f, 0.f, 0.f, 0.f};
    #pragma unroll
    for (int nt = 0; nt < 4; ++nt) {
        const int n = cq * 64 + nt * 16 + m;
        short4v v;
        #pragma unroll
        for (int r2 = 0; r2 < 4; ++r2) v[r2] = f2bf_rn(acc[nt][r2]);
        *(short4v*)(WhT + (size_t)n * N_NODES + i0) = v;
        const float rs = r[n], rd = r[NF + n];
        #pragma unroll
        for (int r2 = 0; r2 < 4; ++r2) {
            vs[r2] = fmaf(acc[nt][r2], rs, vs[r2]);
            vd[r2] = fmaf(acc[nt][r2], rd, vd[r2]);
        }
    }
    #pragma unroll
    for (int mask = 1; mask <= 8; mask <<= 1) {
        #pragma unroll
        for (int r2 = 0; r2 < 4; ++r2) {
            vs[r2] += __shfl_xor(vs[r2], mask);
            vd[r2] += __shfl_xor(vd[r2], mask);
        }
    }
    if (m == 0) {
        #pragma unroll
        for (int r2 = 0; r2 < 4; ++r2) {
            sp_src[cq * N_NODES + i0 + r2] = vs[r2];
            sp_dst[cq * N_NODES + i0 + r2] = vd[r2];
        }
    }
}

// ---------------------------------------------------------------------------
// K2: sum 4 partials -> s_src/s_dst; per-block max(s_dst) -> pmax[32]
// ---------------------------------------------------------------------------
__global__ __launch_bounds__(256) void k2_sv(const float* __restrict__ sp_src,
                                             const float* __restrict__ sp_dst,
                                             float* __restrict__ s_src,
                                             float* __restrict__ s_dst,
                                             float* __restrict__ pmax) {
    __shared__ float red[256];
    const int tid = threadIdx.x;
    const int i = blockIdx.x * 256 + tid;
    float ss = 0.f, sd = 0.f;
    #pragma unroll
    for (int nb = 0; nb < 4; ++nb) {
        ss += sp_src[nb * N_NODES + i];
        sd += sp_dst[nb * N_NODES + i];
    }
    s_src[i] = ss;
    s_dst[i] = sd;
    red[tid] = sd;
    __syncthreads();
    for (int off = 128; off > 0; off >>= 1) {
        if (tid < off) red[tid] = fmaxf(red[tid], red[tid + off]);
        __syncthreads();
    }
    if (tid == 0) pmax[blockIdx.x] = red[0];
}

// ---------------------------------------------------------------------------
// K4 v6: fused masked-softmax attention + PV MFMA — BARRIER-FREE inner loop.
// Round-5 lesson: step cost ~7000 cyc regardless of payload (r3 128j/16w vs
// r5 64j/8w) => fixed per-step latency floor from the barrier-locked staging
// schedule, not a throughput limit (all pipes <30%). Fix: WhT is 4 MB = fits
// XCD L2, so B fragments are read DIRECTLY global->reg (guide lesson #7:
// LDS-staging L2-resident data is pure overhead). The per-lane global address
// WhT[n*8192 + jbase + s*64 + jq*32 + q*8] is bit-identical to the old
// LDS-swizzle round-trip => identical MFMA operands => identical numerics.
// Inner loop: NO barriers, NO LDS, NO DMA, NO waitcnt asm. 8 B-loads (L2-hot,
// hidden under pgroup's independent VALU) + next-step A/t prefetch (HBM, one
// full step of slack) + pgroup + 8 MFMA. Waves free-run; LDS only for the
// one-shot epilogue reduction (exact r5 summation order -> same absmax).
// grid 512 = 256 row-groups x 2 j-halves; 512 thr, 8 waves (rh2 x ch2 x jq2).
// ---------------------------------------------------------------------------
static __device__ __forceinline__ void pgroup(const int4 a, const floatx4 t,
                                              const float s_i, const float d_i,
                                              float* p) {
    const int av[4] = {a.x, a.y, a.z, a.w};
    #pragma unroll
    for (int c = 0; c < 4; ++c) {
        float sum = s_i + t[c];
        float lr  = fmaxf(sum, 0.2f * sum);
        float pp  = __builtin_amdgcn_exp2f(fmaf(lr, L2E, d_i));
        p[c] = (av[c] != 0) ? pp : 0.0f;
    }
}

__global__ __launch_bounds__(512, 4) void k4_attn(const int* __restrict__ Adj,
                                                  const short* __restrict__ WhT,
                                                  const float* __restrict__ s_dst,
                                                  const float* __restrict__ s_src,
                                                  const float* __restrict__ pmax,
                                                  float* __restrict__ pden,
                                                  float* __restrict__ outacc) {
    __shared__ float red[8 * 8 * 4 * 64];   // [wave][nt][reg][lane] = 64 KB
    __shared__ float denred[64];

    const int tid = threadIdx.x;
    const int w = tid >> 6, lane = tid & 63;
    const int q = lane >> 4, m = lane & 15;
    const int rh = w >> 2, ch = (w >> 1) & 1, jq = w & 1;
    const int ib = blockIdx.x & 255;        // row group
    const int jh = blockIdx.x >> 8;         // j half
    const int i0 = ib * 32;
    const int jbase = jh * 4096;
    const int row = i0 + rh * 16 + m;

    float M = pmax[0];
    #pragma unroll
    for (int b = 1; b < 32; ++b) M = fmaxf(M, pmax[b]);
    const float s_i = s_src[row];
    const float e0 = s_i + M;
    const float d_i = -fmaxf(e0, 0.2f * e0) * L2E;   // -c_i*log2e, c_i >= row max

    // ---- B fragment base pointers (L2-resident WhT), one per nt ----
    const short* gBn[8];
    #pragma unroll
    for (int nt = 0; nt < 8; ++nt) {
        const int n = ch * 128 + nt * 16 + m;
        gBn[nt] = WhT + (size_t)n * N_NODES + jbase + jq * 32 + q * 8;
    }

    // ---- A / t pointers (per lane): 8 j per lane per step ----
    const int* Ap = Adj + (size_t)row * N_NODES + jbase + jq * 32 + q * 8;
    const float* tp = s_dst + jbase + jq * 32 + q * 8;

    floatx4 acc[8];
    #pragma unroll
    for (int nt = 0; nt < 8; ++nt) acc[nt] = (floatx4){0.f, 0.f, 0.f, 0.f};
    float den = 0.f;

    // prologue: prefetch A(0)/t(0)
    int4 a0 = *(const int4*)(Ap);
    int4 a1 = *(const int4*)(Ap + 4);
    floatx4 t0 = *(const floatx4*)(tp);
    floatx4 t1 = *(const floatx4*)(tp + 4);

    for (int s = 0; s < 64; ++s) {
        const int go = s * 64;

        // 1) this step's B fragments (L2-hot; arrive under pgroup's VALU)
        short8 cb[8];
        #pragma unroll
        for (int nt = 0; nt < 8; ++nt)
            cb[nt] = *(const short8*)(gBn[nt] + go);
        __builtin_amdgcn_sched_barrier(0);

        // 2) next step's A (HBM, one full step of slack) and t (L2-hot)
        const int gn = ((s + 1) & 63) * 64;
        int4 na0 = *(const int4*)(Ap + gn);
        int4 na1 = *(const int4*)(Ap + gn + 4);
        floatx4 nt0 = *(const floatx4*)(tp + gn);
        floatx4 nt1 = *(const floatx4*)(tp + gn + 4);
        __builtin_amdgcn_sched_barrier(0);

        // 3) P for this step: 8 j per lane (j = jbase + s*64 + jq*32 + q*8 + c)
        float p[8];
        pgroup(a0, t0, s_i, d_i, p);
        pgroup(a1, t1, s_i, d_i, p + 4);

        short8 af;
        #pragma unroll
        for (int c = 0; c < 8; ++c) af[c] = f2bf_rn(p[c]);
        #pragma unroll
        for (int c = 0; c < 8; ++c) den += p[c];

        // 4) PV: 8 MFMAs, k = this wave's 32-j slice, n = 128-wide half
        __builtin_amdgcn_s_setprio(1);
        #pragma unroll
        for (int nt = 0; nt < 8; ++nt)
            acc[nt] = __builtin_amdgcn_mfma_f32_16x16x32_bf16(af, cb[nt], acc[nt], 0, 0, 0);
        __builtin_amdgcn_s_setprio(0);

        a0 = na0; a1 = na1; t0 = nt0; t1 = nt1;
    }

    // ---- epilogue: reduce den over q; reduce acc over the jq pair ----
    den += __shfl_xor(den, 16);
    den += __shfl_xor(den, 32);
    if (ch == 0 && lane < 16) denred[rh * 32 + jq * 16 + lane] = den;
    #pragma unroll
    for (int nt = 0; nt < 8; ++nt)
        #pragma unroll
        for (int rg = 0; rg < 4; ++rg)
            red[((w * 8 + nt) * 4 + rg) * 64 + lane] = acc[nt][rg];
    __syncthreads();

    if (w == 0 && lane < 32) {
        const int rr = lane >> 4, mm = lane & 15;
        pden[jh * N_NODES + i0 + rr * 16 + mm] =
            denred[rr * 32 + mm] + denred[rr * 32 + 16 + mm];
    }
    if (jq == 0) {   // waves 0,2,4,6 combine with partner w+1 (jq=1)
        #pragma unroll
        for (int nt = 0; nt < 8; ++nt) {
            #pragma unroll
            for (int rg = 0; rg < 4; ++rg) {
                float v = red[((w * 8 + nt) * 4 + rg) * 64 + lane]
                        + red[(((w + 1) * 8 + nt) * 4 + rg) * 64 + lane];
                const int orow = i0 + rh * 16 + q * 4 + rg;
                const int n = ch * 128 + nt * 16 + m;
                atomicAdd(&outacc[(size_t)orow * NF + n], v);
            }
        }
    }
}

// ---------------------------------------------------------------------------
// K5: out = gelu(outacc / (pden[0]+pden[1])), in place. 8 elems/thread.
// ---------------------------------------------------------------------------
__global__ __launch_bounds__(256) void k5_fin(const float* __restrict__ pden,
                                              float* __restrict__ out) {
    const int gid = blockIdx.x * 256 + threadIdx.x;
    const int row = gid >> 5;
    const int c0 = (gid & 31) * 8;
    const float d = pden[row] + pden[N_NODES + row];
    const float inv = 1.0f / fmaxf(d, 1e-30f);
    float* p = out + (size_t)row * NF + c0;
    float4 v0 = *(const float4*)(p);
    float4 v1 = *(const float4*)(p + 4);
    float xs[8] = {v0.x, v0.y, v0.z, v0.w, v1.x, v1.y, v1.z, v1.w};
    #pragma unroll
    for (int c = 0; c < 8; ++c) {
        const float x = xs[c] * inv;
        xs[c] = 0.5f * x * (1.0f + erff(x * 0.70710678118f)); // exact GELU
    }
    *(float4*)(p)     = (float4){xs[0], xs[1], xs[2], xs[3]};
    *(float4*)(p + 4) = (float4){xs[4], xs[5], xs[6], xs[7]};
}

// ---------------------------------------------------------------------------
extern "C" void kernel_launch(void* const* d_in, const int* in_sizes, int n_in,
                              void* d_out, int out_size, void* d_ws, size_t ws_size,
                              hipStream_t stream) {
    const float* X = (const float*)d_in[0];   // fp32 8192x256
    const int*   A = (const int*)d_in[1];     // int32 8192x8192
    const float* W = (const float*)d_in[2];   // fp32 256x256
    const float* r = (const float*)d_in[3];   // fp32 512
    float* out = (float*)d_out;

    // ws: WhT bf16 4MB | Whi 128K | Wlo 128K | sp_src 128K | sp_dst 128K |
    //     s_src 32K | s_dst 32K | pmax 128B
    // pden (2*8192 f32 = 64K) ALIASES sp_src: k2 fully consumes sp_src before
    // k4 writes pden (stream-ordered) -> zero workspace growth.
    char* wsp = (char*)d_ws;
    short* WhT    = (short*)wsp;                    wsp += (size_t)NF * N_NODES * 2;
    short* Whi    = (short*)wsp;                    wsp += NF * NF * 2;
    short* Wlo    = (short*)wsp;                    wsp += NF * NF * 2;
    float* sp_src = (float*)wsp;                    wsp += 4 * N_NODES * 4;
    float* sp_dst = (float*)wsp;                    wsp += 4 * N_NODES * 4;
    float* s_src  = (float*)wsp;                    wsp += N_NODES * 4;
    float* s_dst  = (float*)wsp;                    wsp += N_NODES * 4;
    float* pmax   = (float*)wsp;
    float* pden   = sp_src;

    hipMemsetAsync(out, 0, (size_t)N_NODES * NF * 4, stream);
    kx_split<<<64, 256, 0, stream>>>(W, Whi, Wlo);
    k1_gemm<<<256, 512, 0, stream>>>(X, Whi, Wlo, r, WhT, sp_src, sp_dst);
    k2_sv<<<32, 256, 0, stream>>>(sp_src, sp_dst, s_src, s_dst, pmax);
    k4_attn<<<512, 512, 0, stream>>>(A, WhT, s_dst, s_src, pmax, pden, out);
    k5_fin<<<1024, 256, 0, stream>>>(pden, out);
}

// Round 7
// 500.772 us; speedup vs baseline: 1.2577x; 1.2577x over previous
//
#include <hip/hip_runtime.h>
#include <hip/hip_bf16.h>

#define N_NODES 8192
#define NF      256
#define L2E     1.44269504088896341f

typedef __attribute__((ext_vector_type(8))) short short8;
typedef __attribute__((ext_vector_type(4))) short short4v;
typedef __attribute__((ext_vector_type(4))) float floatx4;

static __device__ __forceinline__ float bf2f(short s) {
    return __uint_as_float(((unsigned)(unsigned short)s) << 16);
}
static __device__ __forceinline__ short f2bf_rn(float f) {
    unsigned u = __float_as_uint(f) + 0x8000u;
    return (short)(u >> 16);
}
struct bfpair { short hi, lo; };
static __device__ __forceinline__ bfpair split_bf(float x) {
    bfpair p;
    p.hi = f2bf_rn(x);
    p.lo = f2bf_rn(x - bf2f(p.hi));
    return p;
}
// async global->LDS, 16B/lane, LDS dest = uniform base + lane*16
static __device__ __forceinline__ void async16(const void* g, void* l) {
    __builtin_amdgcn_global_load_lds(
        (const __attribute__((address_space(1))) unsigned*)g,
        (__attribute__((address_space(3))) unsigned*)l, 16, 0, 0);
}

// ---------------------------------------------------------------------------
// KX: split W (256x256 fp32) into bf16 hi/lo arrays, once.
// ---------------------------------------------------------------------------
__global__ __launch_bounds__(256) void kx_split(const float* __restrict__ W,
                                                short* __restrict__ Whi,
                                                short* __restrict__ Wlo) {
    #pragma unroll
    for (int e = 0; e < 4; ++e) {
        const int i = blockIdx.x * 1024 + e * 256 + threadIdx.x;
        bfpair p = split_bf(W[i]);
        Whi[i] = p.hi;
        Wlo[i] = p.lo;
    }
}

// ---------------------------------------------------------------------------
// K1: WhT[n][i] = sum_k X[i][k]*W[n][k] via hi/lo bf16 MFMA (fp32-accurate).
// ---------------------------------------------------------------------------
__global__ __launch_bounds__(512) void k1_gemm(const float* __restrict__ X,
                                               const short* __restrict__ Whi,
                                               const short* __restrict__ Wlo,
                                               const float* __restrict__ r,
                                               short* __restrict__ WhT,
                                               float* __restrict__ sp_src,
                                               float* __restrict__ sp_dst) {
    __shared__ float Xs[32 * 256];   // 32 KB; chunk slot = c ^ (row&7)

    const int tid = threadIdx.x;
    const int w = tid >> 6, lane = tid & 63;
    const int q = lane >> 4, m = lane & 15;
    const int rh = w >> 2, cq = w & 3;
    const int i_base = blockIdx.x * 32;

    // stage 32 rows of X (1 KB each); 4 instrs/wave
    #pragma unroll
    for (int v = 0; v < 4; ++v) {
        const int rowv = w * 4 + v;
        const int c = lane ^ (rowv & 7);
        async16(X + (size_t)(i_base + rowv) * NF + c * 4, &Xs[rowv * 256]);
    }
    __syncthreads();

    floatx4 acc[4] = {};
    const int xrow = rh * 16 + m;
    const int r7 = xrow & 7;
    #pragma unroll
    for (int ks = 0; ks < 8; ++ks) {
        const int c0 = ks * 8 + q * 2;
        float4 f0 = *(const float4*)(&Xs[xrow * 256 + ((c0 ^ r7) * 4)]);
        float4 f1 = *(const float4*)(&Xs[xrow * 256 + (((c0 + 1) ^ r7) * 4)]);
        const float xsv[8] = {f0.x, f0.y, f0.z, f0.w, f1.x, f1.y, f1.z, f1.w};
        short8 xh, xl;
        #pragma unroll
        for (int c = 0; c < 8; ++c) {
            bfpair p = split_bf(xsv[c]);
            xh[c] = p.hi; xl[c] = p.lo;
        }
        #pragma unroll
        for (int nt = 0; nt < 4; ++nt) {
            const int n = cq * 64 + nt * 16 + m;
            short8 wh = *(const short8*)(Whi + n * NF + ks * 32 + q * 8);
            short8 wl = *(const short8*)(Wlo + n * NF + ks * 32 + q * 8);
            acc[nt] = __builtin_amdgcn_mfma_f32_16x16x32_bf16(xh, wh, acc[nt], 0, 0, 0);
            acc[nt] = __builtin_amdgcn_mfma_f32_16x16x32_bf16(xl, wh, acc[nt], 0, 0, 0);
            acc[nt] = __builtin_amdgcn_mfma_f32_16x16x32_bf16(xh, wl, acc[nt], 0, 0, 0);
        }
    }

    // C/D layout: col = lane&15 (n), row = q*4 + reg (i)
    const int i0 = i_base + rh * 16 + q * 4;
    float vs[4] = {0.f, 0.f, 0.f, 0.f}, vd[4] = {0.f, 0.f, 0.f, 0.f};
    #pragma unroll
    for (int nt = 0; nt < 4; ++nt) {
        const int n = cq * 64 + nt * 16 + m;
        short4v v;
        #pragma unroll
        for (int r2 = 0; r2 < 4; ++r2) v[r2] = f2bf_rn(acc[nt][r2]);
        *(short4v*)(WhT + (size_t)n * N_NODES + i0) = v;
        const float rs = r[n], rd = r[NF + n];
        #pragma unroll
        for (int r2 = 0; r2 < 4; ++r2) {
            vs[r2] = fmaf(acc[nt][r2], rs, vs[r2]);
            vd[r2] = fmaf(acc[nt][r2], rd, vd[r2]);
        }
    }
    #pragma unroll
    for (int mask = 1; mask <= 8; mask <<= 1) {
        #pragma unroll
        for (int r2 = 0; r2 < 4; ++r2) {
            vs[r2] += __shfl_xor(vs[r2], mask);
            vd[r2] += __shfl_xor(vd[r2], mask);
        }
    }
    if (m == 0) {
        #pragma unroll
        for (int r2 = 0; r2 < 4; ++r2) {
            sp_src[cq * N_NODES + i0 + r2] = vs[r2];
            sp_dst[cq * N_NODES + i0 + r2] = vd[r2];
        }
    }
}

// ---------------------------------------------------------------------------
// K2: sum 4 partials -> s_src/s_dst; per-block max(s_dst) -> pmax[32]
// ---------------------------------------------------------------------------
__global__ __launch_bounds__(256) void k2_sv(const float* __restrict__ sp_src,
                                             const float* __restrict__ sp_dst,
                                             float* __restrict__ s_src,
                                             float* __restrict__ s_dst,
                                             float* __restrict__ pmax) {
    __shared__ float red[256];
    const int tid = threadIdx.x;
    const int i = blockIdx.x * 256 + tid;
    float ss = 0.f, sd = 0.f;
    #pragma unroll
    for (int nb = 0; nb < 4; ++nb) {
        ss += sp_src[nb * N_NODES + i];
        sd += sp_dst[nb * N_NODES + i];
    }
    s_src[i] = ss;
    s_dst[i] = sd;
    red[tid] = sd;
    __syncthreads();
    for (int off = 128; off > 0; off >>= 1) {
        if (tid < off) red[tid] = fmaxf(red[tid], red[tid + off]);
        __syncthreads();
    }
    if (tid == 0) pmax[blockIdx.x] = red[0];
}

// ---------------------------------------------------------------------------
// K4 v7: fused masked-softmax attention + PV MFMA, 64-ROW BLOCKS.
// Line-rate model (r0-r6 evidence): k4 is VMEM cache-line-request bound
// (~4cyc/64B line/CU; r5: ~1660 lines/CU-step ~= 7000cyc measured; r6's 4x
// B-lines ~= 12800). Lever: amortize the B panel (biggest term) over 2x
// rows. grid 512 = 128 row-groups (64 rows) x 4 j-quarters (2048 j = 32
// steps x 64 j); 1024 thr = 16 waves (rh4 x ch2 x jq2). Per-wave inner loop
// is instruction-identical to r5's proven schedule: pinned [2 stage DMA]->
// [2 A + 2 t prefetch]->pgroup->MFMA(setprio)->vmcnt(4) counted drain->
// s_barrier. B tile [2][256 n][64 j] = 64 KB dbuf; epilogue red (64 KB)
// overlays B. Out combined via exactly-4-way f32 atomicAdd into zeroed out
// (order-independent); pden has 4 partials (aliases sp_src); k5 finishes.
// ---------------------------------------------------------------------------
static __device__ __forceinline__ void pgroup(const int4 a, const floatx4 t,
                                              const float s_i, const float d_i,
                                              float* p) {
    const int av[4] = {a.x, a.y, a.z, a.w};
    #pragma unroll
    for (int c = 0; c < 4; ++c) {
        float sum = s_i + t[c];
        float lr  = fmaxf(sum, 0.2f * sum);
        float pp  = __builtin_amdgcn_exp2f(fmaf(lr, L2E, d_i));
        p[c] = (av[c] != 0) ? pp : 0.0f;
    }
}

__global__ __launch_bounds__(1024, 4) void k4_attn(const int* __restrict__ Adj,
                                                   const short* __restrict__ WhT,
                                                   const float* __restrict__ s_dst,
                                                   const float* __restrict__ s_src,
                                                   const float* __restrict__ pmax,
                                                   float* __restrict__ pden,
                                                   float* __restrict__ outacc) {
    __shared__ union {
        short B[2][256][64];            // [buf][n][64 j-shorts]; slot = c^(n&7)
        float red[4][2][8][4][64];      // [rh][ch][nt][rg][lane] = 64 KB
    } sm;
    __shared__ float denred[128];       // [rh4][jq2][16]

    const int tid = threadIdx.x;
    const int w = tid >> 6, lane = tid & 63;
    const int q = lane >> 4, m = lane & 15;
    const int rh = w >> 2, ch = (w >> 1) & 1, jq = w & 1;
    const int ib = blockIdx.x & 127;        // row group (64 rows)
    const int jh = blockIdx.x >> 7;         // j quarter (0..3)
    const int i0 = ib * 64;
    const int jbase = jh * 2048;
    const int row = i0 + rh * 16 + m;

    float M = pmax[0];
    #pragma unroll
    for (int b = 1; b < 32; ++b) M = fmaxf(M, pmax[b]);
    const float s_i = s_src[row];
    const float e0 = s_i + M;
    const float d_i = -fmaxf(e0, 0.2f * e0) * L2E;   // -c_i*log2e, c_i >= row max

    // ---- B staging: wave stages n-rows [w*16, w*16+16) via 2 DMA instrs ----
    // instr v: 8 rows x 128 B; lane l -> row l>>3, stored slot l&7;
    // logical chunk = (l&7) ^ (n&7), n&7 == l>>3 here.
    const int srow = lane >> 3;
    const int scc = (lane & 7) ^ srow;
    const short* gB[2];
    #pragma unroll
    for (int v = 0; v < 2; ++v)
        gB[v] = WhT + (size_t)(w * 16 + v * 8 + srow) * N_NODES + jbase + scc * 8;

    // ---- A / t pointers (per lane): 8 j per lane per step ----
    const int* Ap = Adj + (size_t)row * N_NODES + jbase + jq * 32 + q * 8;
    const float* tp = s_dst + jbase + jq * 32 + q * 8;

    floatx4 acc[8];
    #pragma unroll
    for (int nt = 0; nt < 8; ++nt) acc[nt] = (floatx4){0.f, 0.f, 0.f, 0.f};
    float den = 0.f;

    // prologue: stage step 0 into buf 0, prefetch A(0)/t(0)
    #pragma unroll
    for (int v = 0; v < 2; ++v)
        async16(gB[v], &sm.B[0][w * 16 + v * 8][0]);
    int4 a0 = *(const int4*)(Ap);
    int4 a1 = *(const int4*)(Ap + 4);
    floatx4 t0 = *(const floatx4*)(tp);
    floatx4 t1 = *(const floatx4*)(tp + 4);
    __syncthreads();

    for (int s = 0; s < 32; ++s) {
        const int cur = s & 1;

        // 1) stage next tile into other buffer (the 2 OLDEST vmem ops)
        short* dstb = &sm.B[cur ^ 1][0][0];
        const int go = ((s + 1) & 31) * 64;   // 64 j per step
        #pragma unroll
        for (int v = 0; v < 2; ++v)
            async16(gB[v] + go, dstb + (w * 16 + v * 8) * 64);
        __builtin_amdgcn_sched_barrier(0);

        // 2) prefetch next step's A (HBM) and t (L2-hot) into registers
        int4 na0 = *(const int4*)(Ap + go);
        int4 na1 = *(const int4*)(Ap + go + 4);
        floatx4 nt0 = *(const floatx4*)(tp + go);
        floatx4 nt1 = *(const floatx4*)(tp + go + 4);
        __builtin_amdgcn_sched_barrier(0);

        // 3) P for this step: 8 j per lane (j = jbase + s*64 + jq*32 + q*8 + c)
        float p[8];
        pgroup(a0, t0, s_i, d_i, p);
        pgroup(a1, t1, s_i, d_i, p + 4);

        short8 af;
        #pragma unroll
        for (int c = 0; c < 8; ++c) af[c] = f2bf_rn(p[c]);
        #pragma unroll
        for (int c = 0; c < 8; ++c) den += p[c];

        // 4) PV: 8 MFMAs, k = this wave's 32-j slice, n = 128-wide half
        const short* Bb = &sm.B[cur][0][0];
        __builtin_amdgcn_s_setprio(1);
        #pragma unroll
        for (int nt = 0; nt < 8; ++nt) {
            const int n = ch * 128 + nt * 16 + m;
            const int sc = (jq * 4 + q) ^ (m & 7);
            short8 b0 = *(const short8*)(Bb + n * 64 + sc * 8);
            acc[nt] = __builtin_amdgcn_mfma_f32_16x16x32_bf16(af, b0, acc[nt], 0, 0, 0);
        }
        __builtin_amdgcn_s_setprio(0);

        // 5) counted wait: drain ONLY the 2 stage DMAs; A/t stay in flight
        __builtin_amdgcn_sched_barrier(0);
        asm volatile("s_waitcnt vmcnt(4)" ::: "memory");
        __builtin_amdgcn_s_barrier();

        a0 = na0; a1 = na1; t0 = nt0; t1 = nt1;
    }

    // ---- epilogue: reduce den over q; reduce acc over the jq pair ----
    den += __shfl_xor(den, 16);
    den += __shfl_xor(den, 32);
    if (ch == 0 && lane < 16) denred[rh * 32 + jq * 16 + lane] = den;
    if (jq == 0) {
        #pragma unroll
        for (int nt = 0; nt < 8; ++nt)
            #pragma unroll
            for (int rg = 0; rg < 4; ++rg)
                sm.red[rh][ch][nt][rg][lane] = acc[nt][rg];
    }
    __syncthreads();

    if (w == 0) {   // 64 lanes cover the block's 64 rows
        const int rr = lane >> 4, mm = lane & 15;
        pden[jh * N_NODES + i0 + rr * 16 + mm] =
            denred[rr * 32 + mm] + denred[rr * 32 + 16 + mm];
    }
    if (jq == 1) {
        #pragma unroll
        for (int nt = 0; nt < 8; ++nt) {
            #pragma unroll
            for (int rg = 0; rg < 4; ++rg) {
                float v = sm.red[rh][ch][nt][rg][lane] + acc[nt][rg];
                const int orow = i0 + rh * 16 + q * 4 + rg;
                const int n = ch * 128 + nt * 16 + m;
                atomicAdd(&outacc[(size_t)orow * NF + n], v);
            }
        }
    }
}

// ---------------------------------------------------------------------------
// K5: out = gelu(outacc / sum_{jh<4} pden[jh]), in place. 8 elems/thread.
// ---------------------------------------------------------------------------
__global__ __launch_bounds__(256) void k5_fin(const float* __restrict__ pden,
                                              float* __restrict__ out) {
    const int gid = blockIdx.x * 256 + threadIdx.x;
    const int row = gid >> 5;
    const int c0 = (gid & 31) * 8;
    const float d = (pden[row] + pden[N_NODES + row]) +
                    (pden[2 * N_NODES + row] + pden[3 * N_NODES + row]);
    const float inv = 1.0f / fmaxf(d, 1e-30f);
    float* p = out + (size_t)row * NF + c0;
    float4 v0 = *(const float4*)(p);
    float4 v1 = *(const float4*)(p + 4);
    float xs[8] = {v0.x, v0.y, v0.z, v0.w, v1.x, v1.y, v1.z, v1.w};
    #pragma unroll
    for (int c = 0; c < 8; ++c) {
        const float x = xs[c] * inv;
        xs[c] = 0.5f * x * (1.0f + erff(x * 0.70710678118f)); // exact GELU
    }
    *(float4*)(p)     = (float4){xs[0], xs[1], xs[2], xs[3]};
    *(float4*)(p + 4) = (float4){xs[4], xs[5], xs[6], xs[7]};
}

// ---------------------------------------------------------------------------
extern "C" void kernel_launch(void* const* d_in, const int* in_sizes, int n_in,
                              void* d_out, int out_size, void* d_ws, size_t ws_size,
                              hipStream_t stream) {
    const float* X = (const float*)d_in[0];   // fp32 8192x256
    const int*   A = (const int*)d_in[1];     // int32 8192x8192
    const float* W = (const float*)d_in[2];   // fp32 256x256
    const float* r = (const float*)d_in[3];   // fp32 512
    float* out = (float*)d_out;

    // ws: WhT bf16 4MB | Whi 128K | Wlo 128K | sp_src 128K | sp_dst 128K |
    //     s_src 32K | s_dst 32K | pmax 128B
    // pden (4*8192 f32 = 128K) ALIASES sp_src exactly: k2 fully consumes
    // sp_src before k4 writes pden (stream-ordered).
    char* wsp = (char*)d_ws;
    short* WhT    = (short*)wsp;                    wsp += (size_t)NF * N_NODES * 2;
    short* Whi    = (short*)wsp;                    wsp += NF * NF * 2;
    short* Wlo    = (short*)wsp;                    wsp += NF * NF * 2;
    float* sp_src = (float*)wsp;                    wsp += 4 * N_NODES * 4;
    float* sp_dst = (float*)wsp;                    wsp += 4 * N_NODES * 4;
    float* s_src  = (float*)wsp;                    wsp += N_NODES * 4;
    float* s_dst  = (float*)wsp;                    wsp += N_NODES * 4;
    float* pmax   = (float*)wsp;
    float* pden   = sp_src;

    hipMemsetAsync(out, 0, (size_t)N_NODES * NF * 4, stream);
    kx_split<<<64, 256, 0, stream>>>(W, Whi, Wlo);
    k1_gemm<<<256, 512, 0, stream>>>(X, Whi, Wlo, r, WhT, sp_src, sp_dst);
    k2_sv<<<32, 256, 0, stream>>>(sp_src, sp_dst, s_src, s_dst, pmax);
    k4_attn<<<512, 1024, 0, stream>>>(A, WhT, s_dst, s_src, pmax, pden, out);
    k5_fin<<<1024, 256, 0, stream>>>(pden, out);
}

// Round 8
// 476.923 us; speedup vs baseline: 1.3206x; 1.0500x over previous
//
#include <hip/hip_runtime.h>
#include <hip/hip_bf16.h>

#define N_NODES 8192
#define NF      256
#define L2E     1.44269504088896341f

typedef __attribute__((ext_vector_type(8))) short short8;
typedef __attribute__((ext_vector_type(4))) short short4v;
typedef __attribute__((ext_vector_type(4))) float floatx4;

static __device__ __forceinline__ float bf2f(short s) {
    return __uint_as_float(((unsigned)(unsigned short)s) << 16);
}
static __device__ __forceinline__ short f2bf_rn(float f) {
    unsigned u = __float_as_uint(f) + 0x8000u;
    return (short)(u >> 16);
}
struct bfpair { short hi, lo; };
static __device__ __forceinline__ bfpair split_bf(float x) {
    bfpair p;
    p.hi = f2bf_rn(x);
    p.lo = f2bf_rn(x - bf2f(p.hi));
    return p;
}
// async global->LDS, 16B/lane, LDS dest = uniform base + lane*16
static __device__ __forceinline__ void async16(const void* g, void* l) {
    __builtin_amdgcn_global_load_lds(
        (const __attribute__((address_space(1))) unsigned*)g,
        (__attribute__((address_space(3))) unsigned*)l, 16, 0, 0);
}

// ---------------------------------------------------------------------------
// KX: split W (256x256 fp32) into bf16 hi/lo arrays, once.
// ---------------------------------------------------------------------------
__global__ __launch_bounds__(256) void kx_split(const float* __restrict__ W,
                                                short* __restrict__ Whi,
                                                short* __restrict__ Wlo) {
    #pragma unroll
    for (int e = 0; e < 4; ++e) {
        const int i = blockIdx.x * 1024 + e * 256 + threadIdx.x;
        bfpair p = split_bf(W[i]);
        Whi[i] = p.hi;
        Wlo[i] = p.lo;
    }
}

// ---------------------------------------------------------------------------
// K1: WhT[n][i] = sum_k X[i][k]*W[n][k] via hi/lo bf16 MFMA (fp32-accurate).
// ---------------------------------------------------------------------------
__global__ __launch_bounds__(512) void k1_gemm(const float* __restrict__ X,
                                               const short* __restrict__ Whi,
                                               const short* __restrict__ Wlo,
                                               const float* __restrict__ r,
                                               short* __restrict__ WhT,
                                               float* __restrict__ sp_src,
                                               float* __restrict__ sp_dst) {
    __shared__ float Xs[32 * 256];   // 32 KB; chunk slot = c ^ (row&7)

    const int tid = threadIdx.x;
    const int w = tid >> 6, lane = tid & 63;
    const int q = lane >> 4, m = lane & 15;
    const int rh = w >> 2, cq = w & 3;
    const int i_base = blockIdx.x * 32;

    // stage 32 rows of X (1 KB each); 4 instrs/wave
    #pragma unroll
    for (int v = 0; v < 4; ++v) {
        const int rowv = w * 4 + v;
        const int c = lane ^ (rowv & 7);
        async16(X + (size_t)(i_base + rowv) * NF + c * 4, &Xs[rowv * 256]);
    }
    __syncthreads();

    floatx4 acc[4] = {};
    const int xrow = rh * 16 + m;
    const int r7 = xrow & 7;
    #pragma unroll
    for (int ks = 0; ks < 8; ++ks) {
        const int c0 = ks * 8 + q * 2;
        float4 f0 = *(const float4*)(&Xs[xrow * 256 + ((c0 ^ r7) * 4)]);
        float4 f1 = *(const float4*)(&Xs[xrow * 256 + (((c0 + 1) ^ r7) * 4)]);
        const float xsv[8] = {f0.x, f0.y, f0.z, f0.w, f1.x, f1.y, f1.z, f1.w};
        short8 xh, xl;
        #pragma unroll
        for (int c = 0; c < 8; ++c) {
            bfpair p = split_bf(xsv[c]);
            xh[c] = p.hi; xl[c] = p.lo;
        }
        #pragma unroll
        for (int nt = 0; nt < 4; ++nt) {
            const int n = cq * 64 + nt * 16 + m;
            short8 wh = *(const short8*)(Whi + n * NF + ks * 32 + q * 8);
            short8 wl = *(const short8*)(Wlo + n * NF + ks * 32 + q * 8);
            acc[nt] = __builtin_amdgcn_mfma_f32_16x16x32_bf16(xh, wh, acc[nt], 0, 0, 0);
            acc[nt] = __builtin_amdgcn_mfma_f32_16x16x32_bf16(xl, wh, acc[nt], 0, 0, 0);
            acc[nt] = __builtin_amdgcn_mfma_f32_16x16x32_bf16(xh, wl, acc[nt], 0, 0, 0);
        }
    }

    // C/D layout: col = lane&15 (n), row = q*4 + reg (i)
    const int i0 = i_base + rh * 16 + q * 4;
    float vs[4] = {0.f, 0.f, 0.f, 0.f}, vd[4] = {0.f, 0.f, 0.f, 0.f};
    #pragma unroll
    for (int nt = 0; nt < 4; ++nt) {
        const int n = cq * 64 + nt * 16 + m;
        short4v v;
        #pragma unroll
        for (int r2 = 0; r2 < 4; ++r2) v[r2] = f2bf_rn(acc[nt][r2]);
        *(short4v*)(WhT + (size_t)n * N_NODES + i0) = v;
        const float rs = r[n], rd = r[NF + n];
        #pragma unroll
        for (int r2 = 0; r2 < 4; ++r2) {
            vs[r2] = fmaf(acc[nt][r2], rs, vs[r2]);
            vd[r2] = fmaf(acc[nt][r2], rd, vd[r2]);
        }
    }
    #pragma unroll
    for (int mask = 1; mask <= 8; mask <<= 1) {
        #pragma unroll
        for (int r2 = 0; r2 < 4; ++r2) {
            vs[r2] += __shfl_xor(vs[r2], mask);
            vd[r2] += __shfl_xor(vd[r2], mask);
        }
    }
    if (m == 0) {
        #pragma unroll
        for (int r2 = 0; r2 < 4; ++r2) {
            sp_src[cq * N_NODES + i0 + r2] = vs[r2];
            sp_dst[cq * N_NODES + i0 + r2] = vd[r2];
        }
    }
}

// ---------------------------------------------------------------------------
// K2: sum 4 partials -> s_src/s_dst; per-block max(s_dst) -> pmax[32]
// ---------------------------------------------------------------------------
__global__ __launch_bounds__(256) void k2_sv(const float* __restrict__ sp_src,
                                             const float* __restrict__ sp_dst,
                                             float* __restrict__ s_src,
                                             float* __restrict__ s_dst,
                                             float* __restrict__ pmax) {
    __shared__ float red[256];
    const int tid = threadIdx.x;
    const int i = blockIdx.x * 256 + tid;
    float ss = 0.f, sd = 0.f;
    #pragma unroll
    for (int nb = 0; nb < 4; ++nb) {
        ss += sp_src[nb * N_NODES + i];
        sd += sp_dst[nb * N_NODES + i];
    }
    s_src[i] = ss;
    s_dst[i] = sd;
    red[tid] = sd;
    __syncthreads();
    for (int off = 128; off > 0; off >>= 1) {
        if (tid < off) red[tid] = fmaxf(red[tid], red[tid + off]);
        __syncthreads();
    }
    if (tid == 0) pmax[blockIdx.x] = red[0];
}

// ---------------------------------------------------------------------------
// K4 v8: 64-row tiles (r7's byte plan) in 8-WAVE domains (r5's execution).
// VMEM-byte model (fits r3/r5/r6 at 11-13 B/cyc/CU = per-CU VMEM ceiling):
// k4 time ~= total_bytes / 7.4 TB/s. r5 moved B 1GB + A 256MB = 170 us floor
// (measured 186 = 91%). This version: B total halves to 512 MB (64-row
// amortization) -> floor ~104 us — executed with the PROVEN 8-wave domain
// (r7's 16-wave domain only sustained 6.5 B/cyc).
// grid 512 = 128 row-groups(64 rows) x 4 j-quarters (2048 j = 32 steps x 64).
// 512 thr = 8 waves (rh4 x ch2); each wave: 16 rows x 128 n x full 64-j step
// (2 k-slices, 16 MFMA) -> NO jq split, NO acc reduction, NO epilogue barrier;
// LDS = B dbuf 64 KB only -> 2 blocks/CU (launch_bounds(512,4) caps 128 VGPR).
// Schedule/step: issue [4 t (oldest, this-step)] -> [4 stage DMA] ->
// [4 A-prefetch (newest)]; compiler's t-wait = vmcnt(8) keeps DMA+A in
// flight; end-of-step vmcnt(4) drains exactly the DMAs; A rides across the
// barrier. Out combined via exactly-4-way f32 atomicAdd (order-independent);
// pden 4 partials (aliases sp_src); k5 finishes.
// ---------------------------------------------------------------------------
static __device__ __forceinline__ void pgroup(const int4 a, const floatx4 t,
                                              const float s_i, const float d_i,
                                              float* p) {
    const int av[4] = {a.x, a.y, a.z, a.w};
    #pragma unroll
    for (int c = 0; c < 4; ++c) {
        float sum = s_i + t[c];
        float lr  = fmaxf(sum, 0.2f * sum);
        float pp  = __builtin_amdgcn_exp2f(fmaf(lr, L2E, d_i));
        p[c] = (av[c] != 0) ? pp : 0.0f;
    }
}

__global__ __launch_bounds__(512, 4) void k4_attn(const int* __restrict__ Adj,
                                                  const short* __restrict__ WhT,
                                                  const float* __restrict__ s_dst,
                                                  const float* __restrict__ s_src,
                                                  const float* __restrict__ pmax,
                                                  float* __restrict__ pden,
                                                  float* __restrict__ outacc) {
    __shared__ short Bs[2][256][64];    // [buf][n][64 j]; 16B slot = c^(n&7); 64 KB

    const int tid = threadIdx.x;
    const int w = tid >> 6, lane = tid & 63;
    const int q = lane >> 4, m = lane & 15;
    const int rh = w >> 1, ch = w & 1;      // 4 rowgroups x 2 n-halves
    const int ib = blockIdx.x & 127;        // row group (64 rows)
    const int jh = blockIdx.x >> 7;         // j quarter (0..3)
    const int i0 = ib * 64;
    const int jbase = jh * 2048;
    const int row = i0 + rh * 16 + m;

    float M = pmax[0];
    #pragma unroll
    for (int b = 1; b < 32; ++b) M = fmaxf(M, pmax[b]);
    const float s_i = s_src[row];
    const float e0 = s_i + M;
    const float d_i = -fmaxf(e0, 0.2f * e0) * L2E;   // -c_i*log2e, c_i >= row max

    // ---- B staging: wave stages n-rows [w*32, w*32+32) via 4 DMA instrs ----
    // instr v: 8 rows x 128 B; lane l -> row l>>3, stored slot l&7;
    // logical chunk = (l&7) ^ (row&7).
    const int srow = lane >> 3;
    const int scc = (lane & 7) ^ srow;
    const short* gB[4];
    #pragma unroll
    for (int v = 0; v < 4; ++v)
        gB[v] = WhT + (size_t)(w * 32 + v * 8 + srow) * N_NODES + jbase + scc * 8;

    // ---- A / t pointers (per lane): 16 j per lane per step (2 k-slices) ----
    const int* Ap = Adj + (size_t)row * N_NODES + jbase + q * 8;
    const float* tp = s_dst + jbase + q * 8;

    floatx4 acc[8];
    #pragma unroll
    for (int nt = 0; nt < 8; ++nt) acc[nt] = (floatx4){0.f, 0.f, 0.f, 0.f};
    float den = 0.f;

    // prologue: stage step 0 into buf 0, prefetch A(0)
    #pragma unroll
    for (int v = 0; v < 4; ++v)
        async16(gB[v], &Bs[0][w * 32 + v * 8][0]);
    int4 a0 = *(const int4*)(Ap);
    int4 a1 = *(const int4*)(Ap + 4);
    int4 a2 = *(const int4*)(Ap + 32);
    int4 a3 = *(const int4*)(Ap + 36);
    __syncthreads();

    for (int s = 0; s < 32; ++s) {
        const int cur = s & 1;
        const int gt = s * 64;

        // 1) t loads for THIS step (the 4 OLDEST vmem ops; L2-hot broadcast)
        floatx4 t0 = *(const floatx4*)(tp + gt);
        floatx4 t1 = *(const floatx4*)(tp + gt + 4);
        floatx4 t2 = *(const floatx4*)(tp + gt + 32);
        floatx4 t3 = *(const floatx4*)(tp + gt + 36);
        __builtin_amdgcn_sched_barrier(0);

        // 2) stage next tile into other buffer (middle 4 vmem ops)
        short* dstb = &Bs[cur ^ 1][0][0];
        const int gn = ((s + 1) & 31) * 64;
        #pragma unroll
        for (int v = 0; v < 4; ++v)
            async16(gB[v] + gn, dstb + (w * 32 + v * 8) * 64);
        __builtin_amdgcn_sched_barrier(0);

        // 3) prefetch next step's A (HBM; the 4 NEWEST — ride across barrier)
        int4 na0 = *(const int4*)(Ap + gn);
        int4 na1 = *(const int4*)(Ap + gn + 4);
        int4 na2 = *(const int4*)(Ap + gn + 32);
        int4 na3 = *(const int4*)(Ap + gn + 36);
        __builtin_amdgcn_sched_barrier(0);

        // 4) P: 16 j per lane (slice0 j=q*8+0..7, slice1 j=32+q*8+0..7)
        //    compiler waits t with vmcnt(8) -> DMA + A stay in flight
        float p[16];
        pgroup(a0, t0, s_i, d_i, p);
        pgroup(a1, t1, s_i, d_i, p + 4);
        pgroup(a2, t2, s_i, d_i, p + 8);
        pgroup(a3, t3, s_i, d_i, p + 12);

        short8 af0, af1;
        #pragma unroll
        for (int c = 0; c < 8; ++c) { af0[c] = f2bf_rn(p[c]); af1[c] = f2bf_rn(p[8 + c]); }
        #pragma unroll
        for (int c = 0; c < 16; ++c) den += p[c];

        // 5) PV: 8 nt x 2 k-slices = 16 MFMAs
        const short* Bb = &Bs[cur][0][0];
        __builtin_amdgcn_s_setprio(1);
        #pragma unroll
        for (int nt = 0; nt < 8; ++nt) {
            const int n = ch * 128 + nt * 16 + m;
            const int sw = m & 7;
            short8 b0 = *(const short8*)(Bb + n * 64 + ((q ^ sw) * 8));
            short8 b1 = *(const short8*)(Bb + n * 64 + (((4 + q) ^ sw) * 8));
            acc[nt] = __builtin_amdgcn_mfma_f32_16x16x32_bf16(af0, b0, acc[nt], 0, 0, 0);
            acc[nt] = __builtin_amdgcn_mfma_f32_16x16x32_bf16(af1, b1, acc[nt], 0, 0, 0);
        }
        __builtin_amdgcn_s_setprio(0);

        // 6) counted wait: drain the 4 stage DMAs; A-prefetch stays in flight
        __builtin_amdgcn_sched_barrier(0);
        asm volatile("s_waitcnt vmcnt(4)" ::: "memory");
        __builtin_amdgcn_s_barrier();

        a0 = na0; a1 = na1; a2 = na2; a3 = na3;
    }

    // ---- epilogue: barrier-free. den: reduce over q (4 lanes per row) ----
    den += __shfl_xor(den, 16);
    den += __shfl_xor(den, 32);
    if (ch == 0 && q == 0) pden[jh * N_NODES + row] = den;

    // out: each (row,n) owned by exactly one wave here; 4-way across jh blocks
    #pragma unroll
    for (int nt = 0; nt < 8; ++nt) {
        #pragma unroll
        for (int rg = 0; rg < 4; ++rg) {
            const int orow = i0 + rh * 16 + q * 4 + rg;
            const int n = ch * 128 + nt * 16 + m;
            atomicAdd(&outacc[(size_t)orow * NF + n], acc[nt][rg]);
        }
    }
}

// ---------------------------------------------------------------------------
// K5: out = gelu(outacc / sum_{jh<4} pden[jh]), in place. 8 elems/thread.
// ---------------------------------------------------------------------------
__global__ __launch_bounds__(256) void k5_fin(const float* __restrict__ pden,
                                              float* __restrict__ out) {
    const int gid = blockIdx.x * 256 + threadIdx.x;
    const int row = gid >> 5;
    const int c0 = (gid & 31) * 8;
    const float d = (pden[row] + pden[N_NODES + row]) +
                    (pden[2 * N_NODES + row] + pden[3 * N_NODES + row]);
    const float inv = 1.0f / fmaxf(d, 1e-30f);
    float* p = out + (size_t)row * NF + c0;
    float4 v0 = *(const float4*)(p);
    float4 v1 = *(const float4*)(p + 4);
    float xs[8] = {v0.x, v0.y, v0.z, v0.w, v1.x, v1.y, v1.z, v1.w};
    #pragma unroll
    for (int c = 0; c < 8; ++c) {
        const float x = xs[c] * inv;
        xs[c] = 0.5f * x * (1.0f + erff(x * 0.70710678118f)); // exact GELU
    }
    *(float4*)(p)     = (float4){xs[0], xs[1], xs[2], xs[3]};
    *(float4*)(p + 4) = (float4){xs[4], xs[5], xs[6], xs[7]};
}

// ---------------------------------------------------------------------------
extern "C" void kernel_launch(void* const* d_in, const int* in_sizes, int n_in,
                              void* d_out, int out_size, void* d_ws, size_t ws_size,
                              hipStream_t stream) {
    const float* X = (const float*)d_in[0];   // fp32 8192x256
    const int*   A = (const int*)d_in[1];     // int32 8192x8192
    const float* W = (const float*)d_in[2];   // fp32 256x256
    const float* r = (const float*)d_in[3];   // fp32 512
    float* out = (float*)d_out;

    // ws: WhT bf16 4MB | Whi 128K | Wlo 128K | sp_src 128K | sp_dst 128K |
    //     s_src 32K | s_dst 32K | pmax 128B
    // pden (4*8192 f32 = 128K) ALIASES sp_src exactly: k2 fully consumes
    // sp_src before k4 writes pden (stream-ordered).
    char* wsp = (char*)d_ws;
    short* WhT    = (short*)wsp;                    wsp += (size_t)NF * N_NODES * 2;
    short* Whi    = (short*)wsp;                    wsp += NF * NF * 2;
    short* Wlo    = (short*)wsp;                    wsp += NF * NF * 2;
    float* sp_src = (float*)wsp;                    wsp += 4 * N_NODES * 4;
    float* sp_dst = (float*)wsp;                    wsp += 4 * N_NODES * 4;
    float* s_src  = (float*)wsp;                    wsp += N_NODES * 4;
    float* s_dst  = (float*)wsp;                    wsp += N_NODES * 4;
    float* pmax   = (float*)wsp;
    float* pden   = sp_src;

    hipMemsetAsync(out, 0, (size_t)N_NODES * NF * 4, stream);
    kx_split<<<64, 256, 0, stream>>>(W, Whi, Wlo);
    k1_gemm<<<256, 512, 0, stream>>>(X, Whi, Wlo, r, WhT, sp_src, sp_dst);
    k2_sv<<<32, 256, 0, stream>>>(sp_src, sp_dst, s_src, s_dst, pmax);
    k4_attn<<<512, 512, 0, stream>>>(A, WhT, s_dst, s_src, pmax, pden, out);
    k5_fin<<<1024, 256, 0, stream>>>(pden, out);
}